// Round 2
// baseline (42297.290 us; speedup 1.0000x reference)
//
#include <hip/hip_runtime.h>
#include <math.h>

#define F4(p) (*reinterpret_cast<const float4*>(p))

constexpr int D    = 512;
constexpr int H    = 8;
constexpr int HD   = 64;
constexpr int NL   = 6;
constexpr int NB   = 64;     // batch
constexpr int M    = 20;     // context length
constexpr int T    = 30;     // max_tokens
constexpr int SMAX = 49;     // 20 + 29 positions
constexpr int NR   = NB * M; // 1280 prefill rows
constexpr float EPS   = 1e-5f;
constexpr float SCALE = 0.125f; // 1/sqrt(64)

#define GM_PLAIN 0
#define GM_QKV   1

__device__ __forceinline__ float gelu_f(float x){
  return 0.5f * x * (1.f + erff(x * 0.70710678118654752f));
}

// dot of K-length LDS vector x with global row w; 8 lanes (j=0..7) cooperate.
template<int K>
__device__ __forceinline__ float dot8(const float* __restrict__ w, const float* x, int j){
  float a0 = 0.f, a1 = 0.f;
  #pragma unroll
  for (int r = 0; r < K/64; r++){
    int d = j*4 + r*64;
    float4 w0 = F4(w + d);        float4 w1 = F4(w + d + 32);
    float4 x0 = F4(x + d);        float4 x1 = F4(x + d + 32);
    a0 += w0.x*x0.x + w0.y*x0.y + w0.z*x0.z + w0.w*x0.w;
    a1 += w1.x*x1.x + w1.y*x1.y + w1.z*x1.z + w1.w*x1.w;
  }
  float a = a0 + a1;
  a += __shfl_xor(a, 4, 8);
  a += __shfl_xor(a, 2, 8);
  a += __shfl_xor(a, 1, 8);
  return a;
}

// 2048-length dot with 16 lanes
__device__ __forceinline__ float dot16_2048(const float* __restrict__ w, const float* x, int j){
  float a0 = 0.f, a1 = 0.f;
  #pragma unroll
  for (int r = 0; r < 16; r++){
    int d = j*4 + r*128;
    float4 w0 = F4(w + d);        float4 w1 = F4(w + d + 64);
    float4 x0 = F4(x + d);        float4 x1 = F4(x + d + 64);
    a0 += w0.x*x0.x + w0.y*x0.y + w0.z*x0.z + w0.w*x0.w;
    a1 += w1.x*x1.x + w1.y*x1.y + w1.z*x1.z + w1.w*x1.w;
  }
  float a = a0 + a1;
  a += __shfl_xor(a, 8, 16);
  a += __shfl_xor(a, 4, 16);
  a += __shfl_xor(a, 2, 16);
  a += __shfl_xor(a, 1, 16);
  return a;
}

// -------------------- prefill kernels (unchanged from round 0) --------------------

__device__ __forceinline__ float wave_sum64(float v){
  #pragma unroll
  for (int o = 32; o > 0; o >>= 1) v += __shfl_down(v, o, 64);
  return v;
}

__device__ __forceinline__ float block_sum256(float v, float* red){
  v = wave_sum64(v);
  int wid = threadIdx.x >> 6, lane = threadIdx.x & 63;
  if (lane == 0) red[wid] = v;
  __syncthreads();
  if (threadIdx.x == 0) red[0] = red[0] + red[1] + red[2] + red[3];
  __syncthreads();
  float tot = red[0];
  __syncthreads();
  return tot;
}

__global__ __launch_bounds__(256) void k_embed(const float* __restrict__ ctx,
    const float* __restrict__ pos, float* __restrict__ X0){
  int r = blockIdx.x, t = threadIdx.x, s = r % M;
  X0[(size_t)r*D + t]       = ctx[(size_t)r*D + t]       + pos[(size_t)s*D + t];
  X0[(size_t)r*D + t + 256] = ctx[(size_t)r*D + t + 256] + pos[(size_t)s*D + t + 256];
}

__global__ __launch_bounds__(256) void k_ln(const float* __restrict__ x, float* __restrict__ y,
    const float* __restrict__ g, const float* __restrict__ bb){
  __shared__ float red[4];
  int r = blockIdx.x, t = threadIdx.x;
  const float* xr = x + (size_t)r*D;
  float v0 = xr[t], v1 = xr[t+256];
  float mean = block_sum256(v0+v1, red) * (1.f/D);
  float d0 = v0-mean, d1 = v1-mean;
  float var = block_sum256(d0*d0 + d1*d1, red) * (1.f/D);
  float rs = rsqrtf(var + EPS);
  float* yr = y + (size_t)r*D;
  yr[t]     = d0*rs*g[t]     + bb[t];
  yr[t+256] = d1*rs*g[t+256] + bb[t+256];
}

__global__ __launch_bounds__(256) void k_gemm(
    const float* __restrict__ A, const float* __restrict__ W,
    const float* __restrict__ bias, const float* __restrict__ res,
    float* __restrict__ C, int K, int ldc, int gelu_flag,
    float* __restrict__ q0, float* __restrict__ kc, float* __restrict__ vc, int mode){
  __shared__ __align__(16) float As[32][64];
  __shared__ __align__(16) float Ws[32][64];
  int m0 = blockIdx.x*64, n0 = blockIdx.y*64;
  int t = threadIdx.x, tx = t & 15, ty = t >> 4;
  float acc[4][4] = {};
  for (int k0 = 0; k0 < K; k0 += 32){
    #pragma unroll
    for (int i = 0; i < 2; i++){
      int idx = t + i*256;
      int m = idx & 63, k4 = idx >> 6;
      float4 a = F4(A + (size_t)(m0+m)*K + k0 + k4*4);
      As[k4*4+0][m]=a.x; As[k4*4+1][m]=a.y; As[k4*4+2][m]=a.z; As[k4*4+3][m]=a.w;
      float4 w = F4(W + (size_t)(n0+m)*K + k0 + k4*4);
      Ws[k4*4+0][m]=w.x; Ws[k4*4+1][m]=w.y; Ws[k4*4+2][m]=w.z; Ws[k4*4+3][m]=w.w;
    }
    __syncthreads();
    #pragma unroll
    for (int k = 0; k < 32; k++){
      float4 a = *reinterpret_cast<float4*>(&As[k][ty*4]);
      float4 w = *reinterpret_cast<float4*>(&Ws[k][tx*4]);
      float av[4] = {a.x,a.y,a.z,a.w};
      float wv[4] = {w.x,w.y,w.z,w.w};
      #pragma unroll
      for (int i = 0; i < 4; i++)
        #pragma unroll
        for (int jj = 0; jj < 4; jj++) acc[i][jj] += av[i]*wv[jj];
    }
    __syncthreads();
  }
  #pragma unroll
  for (int i = 0; i < 4; i++){
    int row = m0 + ty*4 + i;
    #pragma unroll
    for (int jj = 0; jj < 4; jj++){
      int col = n0 + tx*4 + jj;
      float v = acc[i][jj] + bias[col];
      if (res) v += res[(size_t)row*ldc + col];
      if (gelu_flag) v = gelu_f(v);
      if (mode == GM_PLAIN){
        C[(size_t)row*ldc + col] = v;
      } else {
        if (col < D) q0[(size_t)row*D + col] = v;
        else {
          int b = row / M, s = row % M;
          float* dst = (col < 2*D) ? kc : vc;
          dst[((size_t)b*SMAX + s)*D + (col & (D-1))] = v;
        }
      }
    }
  }
}

__global__ __launch_bounds__(256) void k_sattn_pre(const float* __restrict__ Q0,
    const float* __restrict__ kc, const float* __restrict__ vc, float* __restrict__ AT0){
  int b = blockIdx.x >> 3, h = blockIdx.x & 7, t = threadIdx.x;
  __shared__ __align__(16) float q[M][HD], kk[M][HD], vv[M][HD];
  __shared__ float sc[M][M];
  for (int idx = t; idx < M*HD; idx += 256){
    int s = idx >> 6, e = idx & 63;
    q[s][e]  = Q0[((size_t)b*M + s)*D + h*HD + e];
    kk[s][e] = kc[((size_t)b*SMAX + s)*D + h*HD + e];
    vv[s][e] = vc[((size_t)b*SMAX + s)*D + h*HD + e];
  }
  __syncthreads();
  for (int idx = t; idx < M*M; idx += 256){
    int qs = idx / M, ks = idx % M;
    if (ks <= qs){
      float s = 0.f;
      #pragma unroll
      for (int e = 0; e < HD; e++) s += q[qs][e]*kk[ks][e];
      sc[qs][ks] = s * SCALE;
    }
  }
  __syncthreads();
  if (t < M){
    float mx = -1e30f;
    for (int ks = 0; ks <= t; ks++) mx = fmaxf(mx, sc[t][ks]);
    float sum = 0.f;
    for (int ks = 0; ks <= t; ks++){ float e = expf(sc[t][ks]-mx); sc[t][ks] = e; sum += e; }
    float inv = 1.f/sum;
    for (int ks = 0; ks <= t; ks++) sc[t][ks] *= inv;
  }
  __syncthreads();
  for (int idx = t; idx < M*HD; idx += 256){
    int qs = idx >> 6, e = idx & 63;
    float o = 0.f;
    for (int ks = 0; ks <= qs; ks++) o += sc[qs][ks]*vv[ks][e];
    AT0[((size_t)b*M + qs)*D + h*HD + e] = o;
  }
}

__global__ __launch_bounds__(256) void k_cattn_pre(const float* __restrict__ Q0,
    const float* __restrict__ ckv, float* __restrict__ AT0){
  int b = blockIdx.x >> 3, h = blockIdx.x & 7, t = threadIdx.x;
  __shared__ __align__(16) float q[M][HD], kk[M][HD], vv[M][HD];
  __shared__ float sc[M][M];
  for (int idx = t; idx < M*HD; idx += 256){
    int s = idx >> 6, e = idx & 63;
    q[s][e]  = Q0[((size_t)b*M + s)*D + h*HD + e];
    kk[s][e] = ckv[((size_t)b*M + s)*1024 + h*HD + e];
    vv[s][e] = ckv[((size_t)b*M + s)*1024 + D + h*HD + e];
  }
  __syncthreads();
  for (int idx = t; idx < M*M; idx += 256){
    int qs = idx / M, ks = idx % M;
    float s = 0.f;
    #pragma unroll
    for (int e = 0; e < HD; e++) s += q[qs][e]*kk[ks][e];
    sc[qs][ks] = s * SCALE;
  }
  __syncthreads();
  if (t < M){
    float mx = -1e30f;
    for (int ks = 0; ks < M; ks++) mx = fmaxf(mx, sc[t][ks]);
    float sum = 0.f;
    for (int ks = 0; ks < M; ks++){ float e = expf(sc[t][ks]-mx); sc[t][ks] = e; sum += e; }
    float inv = 1.f/sum;
    for (int ks = 0; ks < M; ks++) sc[t][ks] *= inv;
  }
  __syncthreads();
  for (int idx = t; idx < M*HD; idx += 256){
    int qs = idx >> 6, e = idx & 63;
    float o = 0.f;
    for (int ks = 0; ks < M; ks++) o += sc[qs][ks]*vv[ks][e];
    AT0[((size_t)b*M + qs)*D + h*HD + e] = o;
  }
}

// -------------------- decode: one block per batch row, whole decode in one kernel --------------------

__device__ __forceinline__ float bsum1024(float v, float* red, int t){
  #pragma unroll
  for (int o = 32; o > 0; o >>= 1) v += __shfl_xor(v, o, 64);
  if ((t & 63) == 0) red[t >> 6] = v;
  __syncthreads();
  if (t == 0){
    float s = 0.f;
    #pragma unroll
    for (int i = 0; i < 16; i++) s += red[i];
    red[16] = s;
  }
  __syncthreads();
  return red[16];
}

__device__ __forceinline__ void ln_ip(const float* xx, float* yy,
    const float* __restrict__ g, const float* __restrict__ bb, float* red, int t){
  float v = (t < D) ? xx[t] : 0.f;
  float mean = bsum1024(v, red, t) * (1.f/D);
  float dd = (t < D) ? (v - mean) : 0.f;
  float var = bsum1024(dd*dd, red, t) * (1.f/D);
  float rs = rsqrtf(var + EPS);
  if (t < D) yy[t] = dd*rs*g[t] + bb[t];
}

__device__ __forceinline__ void logits_pos(float* x, const float* __restrict__ outw,
    const float* __restrict__ outb, const float* __restrict__ pos,
    float* __restrict__ out, int b, int t, int st, int pn){
  if (t < D){
    int c = t >> 6, lane = t & 63;
    const float* wr = outw + (size_t)c*D + lane*8;
    const float* xr = x + lane*8;
    float4 w0 = F4(wr), w1 = F4(wr + 4);
    float4 x0 = F4(xr), x1 = F4(xr + 4);
    float a = w0.x*x0.x + w0.y*x0.y + w0.z*x0.z + w0.w*x0.w
            + w1.x*x1.x + w1.y*x1.y + w1.z*x1.z + w1.w*x1.w;
    #pragma unroll
    for (int o = 32; o > 0; o >>= 1) a += __shfl_xor(a, o, 64);
    if (lane == 0) out[((size_t)b*T + st)*8 + c] = a + outb[c];
  }
  __syncthreads();
  if (t < D) x[t] += pos[(size_t)pn*D + t];
  __syncthreads();
}

__global__ __launch_bounds__(1024) void k_chain(
    const float* __restrict__ X0, const float* __restrict__ pos,
    const float* __restrict__ sa_w, const float* __restrict__ sa_b,
    const float* __restrict__ sa_ow, const float* __restrict__ sa_ob,
    const float* __restrict__ ca_w, const float* __restrict__ ca_b,
    const float* __restrict__ ca_ow, const float* __restrict__ ca_ob,
    const float* __restrict__ ln1g, const float* __restrict__ ln1b,
    const float* __restrict__ ln2g, const float* __restrict__ ln2b,
    const float* __restrict__ ln3g, const float* __restrict__ ln3b,
    const float* __restrict__ fw1, const float* __restrict__ fb1,
    const float* __restrict__ fw2, const float* __restrict__ fb2,
    const float* __restrict__ outw, const float* __restrict__ outb,
    float* __restrict__ kcache, float* __restrict__ vcache,
    const float* __restrict__ ckv, float* __restrict__ out)
{
  const int b = blockIdx.x, t = threadIdx.x;
  const int j8 = t & 7, j16 = t & 15;
  __shared__ __align__(16) float x[D], xn[D], q[D], at[D], kcur[D], vcur[D];
  __shared__ __align__(16) float hh[2048];
  __shared__ float sc[H][SMAX + 7];
  __shared__ float red[17];

  if (t < D) x[t] = X0[((size_t)b*M + (M-1))*D + t];
  __syncthreads();

  logits_pos(x, outw, outb, pos, out, b, t, 0, M);

  for (int st = 1; st < T; st++){
    const int p = M - 1 + st, S = p + 1;
    for (int l = 0; l < NL; l++){
      float* kb = kcache + ((size_t)l*NB + b)*SMAX*D;
      float* vb = vcache + ((size_t)l*NB + b)*SMAX*D;
      const float* cb_ = ckv + ((size_t)l*NB + b)*M*1024;

      // LN1
      ln_ip(x, xn, ln1g + l*D, ln1b + l*D, red, t);
      __syncthreads();

      // QKV projection (1536 outputs), append K/V to cache + keep in LDS
      {
        const float* w = sa_w + (size_t)l*3*D*D;
        const float* bias = sa_b + (size_t)l*3*D;
        for (int pass = 0; pass < 12; pass++){
          int o = pass*128 + (t >> 3);
          float r = dot8<512>(w + (size_t)o*D, xn, j8);
          if (j8 == 0){
            r += bias[o];
            if (o < D) q[o] = r;
            else if (o < 2*D){ kcur[o-D] = r; kb[(size_t)p*D + (o-D)] = r; }
            else { vcur[o-2*D] = r; vb[(size_t)p*D + (o-2*D)] = r; }
          }
        }
      }
      __syncthreads();

      // self-attn scores: head = t>>7 (8 groups of 128 threads = 16 key-slots of 8 lanes)
      {
        int h = t >> 7, kslot = (t & 127) >> 3;
        const float* qh = q + h*HD;
        float4 x0 = F4(qh + j8*4), x1 = F4(qh + j8*4 + 32);
        for (int ks = kslot; ks < S; ks += 16){
          const float* kr = (ks == p) ? (kcur + h*HD) : (kb + (size_t)ks*D + h*HD);
          float4 w0 = F4(kr + j8*4), w1 = F4(kr + j8*4 + 32);
          float a = w0.x*x0.x + w0.y*x0.y + w0.z*x0.z + w0.w*x0.w
                  + w1.x*x1.x + w1.y*x1.y + w1.z*x1.z + w1.w*x1.w;
          a += __shfl_xor(a, 4, 8); a += __shfl_xor(a, 2, 8); a += __shfl_xor(a, 1, 8);
          if (j8 == 0) sc[h][ks] = a * SCALE;
        }
      }
      __syncthreads();
      // softmax: one wave per head
      if ((t >> 6) < H){
        int h = t >> 6, lane = t & 63;
        float v = (lane < S) ? sc[h][lane] : -1e30f;
        float mx = v;
        #pragma unroll
        for (int o = 32; o > 0; o >>= 1) mx = fmaxf(mx, __shfl_xor(mx, o, 64));
        float e = (lane < S) ? expf(v - mx) : 0.f;
        float sum = e;
        #pragma unroll
        for (int o = 32; o > 0; o >>= 1) sum += __shfl_xor(sum, o, 64);
        if (lane < S) sc[h][lane] = e / sum;
      }
      __syncthreads();
      // AV
      if (t < D){
        int h = t >> 6, e = t & 63;
        float o2 = 0.f;
        for (int ks = 0; ks < p; ks++) o2 += sc[h][ks] * vb[(size_t)ks*D + h*HD + e];
        o2 += sc[h][p] * vcur[h*HD + e];
        at[t] = o2;
      }
      __syncthreads();

      // out-proj + residual into x
      {
        const float* w = sa_ow + (size_t)l*D*D;
        const float* bias = sa_ob + (size_t)l*D;
        for (int pass = 0; pass < 4; pass++){
          int o = pass*128 + (t >> 3);
          float r = dot8<512>(w + (size_t)o*D, at, j8);
          if (j8 == 0) x[o] += r + bias[o];
        }
      }
      __syncthreads();

      // LN2
      ln_ip(x, xn, ln2g + l*D, ln2b + l*D, red, t);
      __syncthreads();

      // cross-q projection
      {
        const float* w = ca_w + (size_t)l*3*D*D;
        const float* bias = ca_b + (size_t)l*3*D;
        for (int pass = 0; pass < 4; pass++){
          int o = pass*128 + (t >> 3);
          float r = dot8<512>(w + (size_t)o*D, xn, j8);
          if (j8 == 0) q[o] = r + bias[o];
        }
      }
      __syncthreads();

      // cross-attn scores (20 keys)
      {
        int h = t >> 7, kslot = (t & 127) >> 3;
        const float* qh = q + h*HD;
        float4 x0 = F4(qh + j8*4), x1 = F4(qh + j8*4 + 32);
        for (int ks = kslot; ks < M; ks += 16){
          const float* kr = cb_ + (size_t)ks*1024 + h*HD;
          float4 w0 = F4(kr + j8*4), w1 = F4(kr + j8*4 + 32);
          float a = w0.x*x0.x + w0.y*x0.y + w0.z*x0.z + w0.w*x0.w
                  + w1.x*x1.x + w1.y*x1.y + w1.z*x1.z + w1.w*x1.w;
          a += __shfl_xor(a, 4, 8); a += __shfl_xor(a, 2, 8); a += __shfl_xor(a, 1, 8);
          if (j8 == 0) sc[h][ks] = a * SCALE;
        }
      }
      __syncthreads();
      if ((t >> 6) < H){
        int h = t >> 6, lane = t & 63;
        float v = (lane < M) ? sc[h][lane] : -1e30f;
        float mx = v;
        #pragma unroll
        for (int o = 32; o > 0; o >>= 1) mx = fmaxf(mx, __shfl_xor(mx, o, 64));
        float e = (lane < M) ? expf(v - mx) : 0.f;
        float sum = e;
        #pragma unroll
        for (int o = 32; o > 0; o >>= 1) sum += __shfl_xor(sum, o, 64);
        if (lane < M) sc[h][lane] = e / sum;
      }
      __syncthreads();
      if (t < D){
        int h = t >> 6, e = t & 63;
        float o2 = 0.f;
        for (int ks = 0; ks < M; ks++) o2 += sc[h][ks] * cb_[(size_t)ks*1024 + D + h*HD + e];
        at[t] = o2;
      }
      __syncthreads();

      // cross out-proj + residual
      {
        const float* w = ca_ow + (size_t)l*D*D;
        const float* bias = ca_ob + (size_t)l*D;
        for (int pass = 0; pass < 4; pass++){
          int o = pass*128 + (t >> 3);
          float r = dot8<512>(w + (size_t)o*D, at, j8);
          if (j8 == 0) x[o] += r + bias[o];
        }
      }
      __syncthreads();

      // LN3
      ln_ip(x, xn, ln3g + l*D, ln3b + l*D, red, t);
      __syncthreads();

      // FFN1 (2048 outputs) + GELU
      {
        const float* w = fw1 + (size_t)l*2048*D;
        const float* bias = fb1 + (size_t)l*2048;
        for (int pass = 0; pass < 16; pass++){
          int o = pass*128 + (t >> 3);
          float r = dot8<512>(w + (size_t)o*D, xn, j8);
          if (j8 == 0) hh[o] = gelu_f(r + bias[o]);
        }
      }
      __syncthreads();

      // FFN2 (512 outputs, K=2048) + residual
      {
        const float* w = fw2 + (size_t)l*D*2048;
        const float* bias = fb2 + (size_t)l*D;
        for (int pass = 0; pass < 8; pass++){
          int o = pass*64 + (t >> 4);
          float r = dot16_2048(w + (size_t)o*2048, hh, j16);
          if (j16 == 0) x[o] += r + bias[o];
        }
      }
      __syncthreads();
    }
    logits_pos(x, outw, outb, pos, out, b, t, st, M + st);
  }
}

// -------------------- host --------------------

extern "C" void kernel_launch(void* const* d_in, const int* in_sizes, int n_in,
                              void* d_out, int out_size, void* d_ws, size_t ws_size,
                              hipStream_t stream){
  (void)in_sizes; (void)n_in; (void)out_size; (void)ws_size;
  const float* ctx   = (const float*)d_in[0];
  const float* pos   = (const float*)d_in[1];
  const float* sa_w  = (const float*)d_in[2];
  const float* sa_b  = (const float*)d_in[3];
  const float* sa_ow = (const float*)d_in[4];
  const float* sa_ob = (const float*)d_in[5];
  const float* ca_w  = (const float*)d_in[6];
  const float* ca_b  = (const float*)d_in[7];
  const float* ca_ow = (const float*)d_in[8];
  const float* ca_ob = (const float*)d_in[9];
  const float* ln1g  = (const float*)d_in[10];
  const float* ln1b  = (const float*)d_in[11];
  const float* ln2g  = (const float*)d_in[12];
  const float* ln2b  = (const float*)d_in[13];
  const float* ln3g  = (const float*)d_in[14];
  const float* ln3b  = (const float*)d_in[15];
  const float* fw1   = (const float*)d_in[16];
  const float* fb1   = (const float*)d_in[17];
  const float* fw2   = (const float*)d_in[18];
  const float* fb2   = (const float*)d_in[19];
  const float* outw  = (const float*)d_in[20];
  const float* outb  = (const float*)d_in[21];
  float* out = (float*)d_out;

  float* w = (float*)d_ws;
  size_t off = 0;
  auto alloc = [&](size_t n){ float* p = w + off; off += n; return p; };
  float* kcache = alloc((size_t)NL*NB*SMAX*D);
  float* vcache = alloc((size_t)NL*NB*SMAX*D);
  float* ckv    = alloc((size_t)NL*NB*M*1024);
  float* X0     = alloc((size_t)NR*D);
  float* XN0    = alloc((size_t)NR*D);
  float* Q0     = alloc((size_t)NR*D);
  float* AT0    = alloc((size_t)NR*D);
  float* H0     = alloc((size_t)NR*2048);

  dim3 blk(256);

  // embed + one-time cross K/V for all layers
  k_embed<<<NR, blk, 0, stream>>>(ctx, pos, X0);
  for (int l = 0; l < NL; l++){
    k_gemm<<<dim3(NR/64, 1024/64), blk, 0, stream>>>(
        ctx, ca_w + (size_t)l*3*D*D + (size_t)D*D, ca_b + (size_t)l*3*D + D, nullptr,
        ckv + (size_t)l*NB*M*1024, 512, 1024, 0, nullptr, nullptr, nullptr, GM_PLAIN);
  }

  // ---- prefill ----
  for (int l = 0; l < NL; l++){
    const float* saw = sa_w + (size_t)l*3*D*D;
    const float* sab = sa_b + (size_t)l*3*D;
    float* kcl = kcache + (size_t)l*NB*SMAX*D;
    float* vcl = vcache + (size_t)l*NB*SMAX*D;
    const float* ckl = ckv + (size_t)l*NB*M*1024;

    k_ln<<<NR, blk, 0, stream>>>(X0, XN0, ln1g + l*D, ln1b + l*D);
    k_gemm<<<dim3(NR/64, 1536/64), blk, 0, stream>>>(
        XN0, saw, sab, nullptr, nullptr, 512, D, 0, Q0, kcl, vcl, GM_QKV);
    k_sattn_pre<<<NB*H, blk, 0, stream>>>(Q0, kcl, vcl, AT0);
    k_gemm<<<dim3(NR/64, D/64), blk, 0, stream>>>(
        AT0, sa_ow + (size_t)l*D*D, sa_ob + l*D, X0, X0, 512, D, 0,
        nullptr, nullptr, nullptr, GM_PLAIN);
    k_ln<<<NR, blk, 0, stream>>>(X0, XN0, ln2g + l*D, ln2b + l*D);
    k_gemm<<<dim3(NR/64, D/64), blk, 0, stream>>>(
        XN0, ca_w + (size_t)l*3*D*D, ca_b + (size_t)l*3*D, nullptr, Q0, 512, D, 0,
        nullptr, nullptr, nullptr, GM_PLAIN);
    k_cattn_pre<<<NB*H, blk, 0, stream>>>(Q0, ckl, AT0);
    k_gemm<<<dim3(NR/64, D/64), blk, 0, stream>>>(
        AT0, ca_ow + (size_t)l*D*D, ca_ob + l*D, X0, X0, 512, D, 0,
        nullptr, nullptr, nullptr, GM_PLAIN);
    k_ln<<<NR, blk, 0, stream>>>(X0, XN0, ln3g + l*D, ln3b + l*D);
    k_gemm<<<dim3(NR/64, 2048/64), blk, 0, stream>>>(
        XN0, fw1 + (size_t)l*2048*D, fb1 + (size_t)l*2048, nullptr, H0, 512, 2048, 1,
        nullptr, nullptr, nullptr, GM_PLAIN);
    k_gemm<<<dim3(NR/64, D/64), blk, 0, stream>>>(
        H0, fw2 + (size_t)l*D*2048, fb2 + l*D, X0, X0, 2048, D, 0,
        nullptr, nullptr, nullptr, GM_PLAIN);
  }

  // ---- decode: one kernel, one block per batch row ----
  k_chain<<<NB, dim3(1024), 0, stream>>>(
      X0, pos, sa_w, sa_b, sa_ow, sa_ob, ca_w, ca_b, ca_ow, ca_ob,
      ln1g, ln1b, ln2g, ln2b, ln3g, ln3b, fw1, fb1, fw2, fb2,
      outw, outb, kcache, vcache, ckv, out);
}